// Round 6
// baseline (430.235 us; speedup 1.0000x reference)
//
#include <hip/hip_runtime.h>
#include <hip/hip_bf16.h>

typedef unsigned short u16;
typedef __attribute__((ext_vector_type(4))) float f32x4;
typedef __attribute__((ext_vector_type(8))) short bf16x8;

#define NE 3072
#define DM 128
#define NH 8
#define HD 16
#define NL 3
#define NR 64
#define FF 512
#define CUT 10.0f
#define CAP 96

// packed bf16 weight layout offsets (per layer, in elements)
#define PK_QKV_A 0
#define PK_WO_A  49152
#define PK_QKV_E 65536
#define PK_WO_E  114688
#define PK_W1    131072
#define PK_W2    196608
#define PK_WRBF  262144
#define PK_LAYER 270336

__device__ __forceinline__ short f2b(float f) {
    unsigned u = __float_as_uint(f);
    unsigned r = (u + 0x7FFFu + ((u >> 16) & 1u)) >> 16;
    return (short)r;
}

// A fragment from row-major f32: lane l -> row (l&15), k = kbase+8*(l>>4)+i
__device__ __forceinline__ bf16x8 load_a(const float* A, int rowoff, int kbase) {
    const float4* p = reinterpret_cast<const float4*>(A + rowoff + kbase);
    float4 f0 = p[0], f1 = p[1];
    bf16x8 r;
    r[0] = f2b(f0.x); r[1] = f2b(f0.y); r[2] = f2b(f0.z); r[3] = f2b(f0.w);
    r[4] = f2b(f1.x); r[5] = f2b(f1.y); r[6] = f2b(f1.z); r[7] = f2b(f1.w);
    return r;
}

// ---------------- pack all weights into bf16 fragment-linear layout ----------------
struct WSrc { const float* W[11]; };

__global__ __launch_bounds__(256)
void pack_w(WSrc ws, short* __restrict__ dst) {
    int gid = blockIdx.x * 256 + threadIdx.x;
    if (gid >= NL * PK_LAYER) return;
    int layer = gid / PK_LAYER, e = gid % PK_LAYER;
    int kind, off, K, N;
    if (e < 49152)       { kind = e / 16384;            off = e % 16384;      K = 128; N = 128; }
    else if (e < 65536)  { kind = 3;                    off = e - 49152;      K = 128; N = 128; }
    else if (e < 114688) { kind = 4 + (e - 65536) / 16384; off = (e - 65536) % 16384; K = 128; N = 128; }
    else if (e < 131072) { kind = 7;                    off = e - 114688;     K = 128; N = 128; }
    else if (e < 196608) { kind = 8;                    off = e - 131072;     K = 128; N = 512; }
    else if (e < 262144) { kind = 9;                    off = e - 196608;     K = 512; N = 128; }
    else                 { kind = 10;                   off = e - 262144;     K = 64;  N = 128; }
    int i = off & 7, lane = (off >> 3) & 63, ft = off >> 9;
    int KT = K >> 5;
    int kt = ft % KT, nt = ft / KT;
    int n = nt * 16 + (lane & 15);
    int k = kt * 32 + 8 * (lane >> 4) + i;
    const float* W = ws.W[kind] + (size_t)layer * K * N;
    dst[gid] = f2b(W[k * N + n]);
}

// ---------------- prep: meta, h=ef, x=ec, rbf ----------------
__global__ __launch_bounds__(64)
void prep_kernel(const float* __restrict__ ef, const float* __restrict__ ec,
                 const int* __restrict__ eidx, const float* __restrict__ nc,
                 const int* __restrict__ bids,
                 float* __restrict__ h, float* __restrict__ x,
                 float* __restrict__ rbf, int4* __restrict__ meta) {
    int e = blockIdx.x, lane = threadIdx.x;
    int s = eidx[e], d = eidx[NE + e];
    if (lane == 0) meta[e] = make_int4(s, d, bids[s], bids[d]);
    h[e * DM + lane]      = ef[e * DM + lane];
    h[e * DM + 64 + lane] = ef[e * DM + 64 + lane];
    if (lane < 3) x[e * 3 + lane] = ec[e * 3 + lane];
    float dx = nc[d * 3 + 0] - nc[s * 3 + 0];
    float dy = nc[d * 3 + 1] - nc[s * 3 + 1];
    float dz = nc[d * 3 + 2] - nc[s * 3 + 2];
    float dist = sqrtf(dx * dx + dy * dy + dz * dz);
    float t = fminf(fmaxf(dist / CUT, 0.f), 1.f);
    float fc = 0.5f * (cosf(3.14159265358979f * t) + 1.f);
    float width = CUT / NR;
    float center = (CUT * lane) / (NR - 1);
    float u = (dist - center) / width;
    rbf[e * NR + lane] = expf(-u * u) * fc;
}

// ---------------- build neighbor lists ----------------
__global__ __launch_bounds__(64)
void build_lists(const int4* __restrict__ meta,
                 u16* __restrict__ idx_a, int* __restrict__ cnt_a,
                 u16* __restrict__ idx_e, int* __restrict__ cnt_e) {
    __shared__ int ca, ce;
    __shared__ u16 ba[CAP], be[CAP];
    int i = blockIdx.x, lane = threadIdx.x;
    if (lane == 0) { ca = 0; ce = 0; }
    __syncthreads();
    int4 mi = meta[i];
    for (int j = lane; j < NE; j += 64) {
        int4 mj = meta[j];
        bool intra_b = (mi.z == mj.z) && (mi.w == mj.w);
        bool share = (mi.x == mj.x) || (mi.x == mj.y) ||
                     (mi.y == mj.x) || (mi.y == mj.y);
        bool oka = intra_b || (i == j);
        bool oke = (share && !intra_b) || (i == j);
        if (oka) { int p = atomicAdd(&ca, 1); if (p < CAP) ba[p] = (u16)j; }
        if (oke) { int p = atomicAdd(&ce, 1); if (p < CAP) be[p] = (u16)j; }
    }
    __syncthreads();
    int na = min(ca, CAP), ne_ = min(ce, CAP);
    if (lane == 0) { cnt_a[i] = na; cnt_e[i] = ne_; }
    for (int p = lane; p < na; p += 64) idx_a[i * CAP + p] = ba[p];
    for (int p = lane; p < ne_; p += 64) idx_e[i * CAP + p] = be[p];
}

// ---------------- QKV projection, 1 wave per block: 16 rows x 128 cols ----------------
// RBF=true: hn = h + rbf@Wrbf (written by y==0), and QKV computed from hn
template <bool RBF>
__global__ __launch_bounds__(64)
void qkv_mfma(const float* __restrict__ h, const float* __restrict__ rbf,
              const short* __restrict__ pQKV, const short* __restrict__ pWr,
              float* __restrict__ hn,
              float* __restrict__ q, float* __restrict__ k2, float* __restrict__ v) {
    __shared__ float hs[16][136];
    int l = threadIdx.x;
    int m0 = blockIdx.x * 16, y = blockIdx.y;
    int arow = m0 + (l & 15);
    int R4 = 4 * (l >> 4), c0 = l & 15;
    const short* Bsec = pQKV + y * 16384;

    if (RBF) {
        f32x4 acc[8];
#pragma unroll
        for (int t = 0; t < 8; t++) acc[t] = {0.f, 0.f, 0.f, 0.f};
#pragma unroll
        for (int kt = 0; kt < 2; kt++) {
            bf16x8 av = load_a(rbf, arow * NR, kt * 32 + 8 * (l >> 4));
#pragma unroll
            for (int t = 0; t < 8; t++) {
                bf16x8 bv = *reinterpret_cast<const bf16x8*>(pWr + (t * 2 + kt) * 512 + l * 8);
                acc[t] = __builtin_amdgcn_mfma_f32_16x16x32_bf16(av, bv, acc[t], 0, 0, 0);
            }
        }
#pragma unroll
        for (int t = 0; t < 8; t++)
#pragma unroll
            for (int r = 0; r < 4; r++) {
                float z = acc[t][r] + h[(m0 + R4 + r) * DM + 16 * t + c0];
                hs[R4 + r][16 * t + c0] = z;
                if (y == 0) hn[(m0 + R4 + r) * DM + 16 * t + c0] = z;
            }
        __syncthreads();
    }

    f32x4 o[8];
#pragma unroll
    for (int t = 0; t < 8; t++) o[t] = {0.f, 0.f, 0.f, 0.f};
#pragma unroll
    for (int kt = 0; kt < 4; kt++) {
        bf16x8 av;
        if (RBF) {
            const float4* pp = reinterpret_cast<const float4*>(&hs[l & 15][kt * 32 + 8 * (l >> 4)]);
            float4 f0 = pp[0], f1 = pp[1];
            av[0] = f2b(f0.x); av[1] = f2b(f0.y); av[2] = f2b(f0.z); av[3] = f2b(f0.w);
            av[4] = f2b(f1.x); av[5] = f2b(f1.y); av[6] = f2b(f1.z); av[7] = f2b(f1.w);
        } else {
            av = load_a(h, arow * DM, kt * 32 + 8 * (l >> 4));
        }
#pragma unroll
        for (int t = 0; t < 8; t++) {
            bf16x8 bv = *reinterpret_cast<const bf16x8*>(Bsec + (t * 4 + kt) * 512 + l * 8);
            o[t] = __builtin_amdgcn_mfma_f32_16x16x32_bf16(av, bv, o[t], 0, 0, 0);
        }
    }
    float* outs = (y == 0) ? q : (y == 1) ? k2 : v;
#pragma unroll
    for (int t = 0; t < 8; t++)
#pragma unroll
        for (int r = 0; r < 4; r++)
            outs[(m0 + R4 + r) * DM + 16 * t + c0] = o[t][r];
}

// ---------------- fused attention + Wo proj + residual + LN, one block per row ----------------
template <bool INTRA>
__global__ __launch_bounds__(512)
void attn_wo_ln(const float* __restrict__ q, const float* __restrict__ k,
                const float* __restrict__ v, const float* __restrict__ xw,
                const u16* __restrict__ idx, const int* __restrict__ cnt,
                const float* __restrict__ Wo, const float* __restrict__ hres,
                float* __restrict__ hout, const float* __restrict__ g,
                const float* __restrict__ b, float* __restrict__ px_part) {
    __shared__ float o_s[DM];
    __shared__ float red[2];
    int i = blockIdx.x;
    int head = threadIdx.x >> 6, lane = threadIdx.x & 63;

    float qreg[HD];
    const float* qp = q + i * DM + head * HD;
#pragma unroll
    for (int d = 0; d < HD; d++) qreg[d] = qp[d];

    int n = cnt[i];
    float m = -1e30f, l = 0.f;
    float acc[HD + 3];
#pragma unroll
    for (int d = 0; d < HD + 3; d++) acc[d] = 0.f;

    for (int p = lane; p < n; p += 64) {
        int j = idx[i * CAP + p];
        const float* kp = k + j * DM + head * HD;
        float s = 0.f;
#pragma unroll
        for (int d = 0; d < HD; d++) s += qreg[d] * kp[d];
        s *= 0.25f;
        if (s > m) {
            float corr = __expf(m - s);
            m = s; l *= corr;
#pragma unroll
            for (int d = 0; d < HD + 3; d++) acc[d] *= corr;
        }
        float pw = __expf(s - m);
        l += pw;
        const float* vp = v + j * DM + head * HD;
#pragma unroll
        for (int d = 0; d < HD; d++) acc[d] += pw * vp[d];
        if (INTRA) {
            const float* xp = xw + j * 3;
#pragma unroll
            for (int c = 0; c < 3; c++) acc[HD + c] += pw * xp[c];
        }
    }
    float mAll = m;
#pragma unroll
    for (int off = 32; off; off >>= 1) mAll = fmaxf(mAll, __shfl_xor(mAll, off));
    float cf = __expf(m - mAll);
    l *= cf;
#pragma unroll
    for (int d = 0; d < HD + 3; d++) acc[d] *= cf;
#pragma unroll
    for (int off = 32; off; off >>= 1) {
        l += __shfl_xor(l, off);
#pragma unroll
        for (int d = 0; d < HD + 3; d++) acc[d] += __shfl_xor(acc[d], off);
    }
    if (lane == 0) {
        float inv = 1.f / l;
#pragma unroll
        for (int d = 0; d < HD; d++) o_s[head * HD + d] = acc[d] * inv;
        if (INTRA) {
            float* pp = px_part + (head * NE + i) * 3;
            pp[0] = acc[HD + 0] * inv;
            pp[1] = acc[HD + 1] * inv;
            pp[2] = acc[HD + 2] * inv;
        }
    }
    __syncthreads();

    // Wo projection + residual + LN on threads 0..127
    int t = threadIdx.x;
    float z = 0.f;
    if (t < DM) {
        float dot = 0.f;
#pragma unroll 8
        for (int kk = 0; kk < DM; kk++) dot += o_s[kk] * Wo[kk * DM + t];
        z = hres[i * DM + t] + dot;
    }
    float s = (t < DM) ? z : 0.f;
#pragma unroll
    for (int off = 32; off; off >>= 1) s += __shfl_xor(s, off);
    if (t < DM && (t & 63) == 0) red[t >> 6] = s;
    __syncthreads();
    float mean = (red[0] + red[1]) * (1.f / DM);
    __syncthreads();
    float d = (t < DM) ? (z - mean) : 0.f;
    float vs = d * d;
#pragma unroll
    for (int off = 32; off; off >>= 1) vs += __shfl_xor(vs, off);
    if (t < DM && (t & 63) == 0) red[t >> 6] = vs;
    __syncthreads();
    if (t < DM) {
        float var = (red[0] + red[1]) * (1.f / DM);
        float inv = rsqrtf(var + 1e-5f);
        hout[i * DM + t] = d * inv * g[t] + b[t];
    }
}

// ---------------- FFN GEMM1 + silu -> u (bf16 row-major [NE][FF]) ----------------
__global__ __launch_bounds__(64)
void ffn1_mfma(const float* __restrict__ h, const short* __restrict__ pW1,
               const float* __restrict__ b1, short* __restrict__ u) {
    int l = threadIdx.x;
    int m0 = blockIdx.x * 16, y = blockIdx.y;
    int arow = m0 + (l & 15);
    f32x4 acc[8];
#pragma unroll
    for (int t = 0; t < 8; t++) acc[t] = {0.f, 0.f, 0.f, 0.f};
#pragma unroll
    for (int kt = 0; kt < 4; kt++) {
        bf16x8 av = load_a(h, arow * DM, kt * 32 + 8 * (l >> 4));
#pragma unroll
        for (int t = 0; t < 8; t++) {
            bf16x8 bv = *reinterpret_cast<const bf16x8*>(pW1 + ((y * 8 + t) * 4 + kt) * 512 + l * 8);
            acc[t] = __builtin_amdgcn_mfma_f32_16x16x32_bf16(av, bv, acc[t], 0, 0, 0);
        }
    }
    int R4 = 4 * (l >> 4), c0 = l & 15;
#pragma unroll
    for (int t = 0; t < 8; t++) {
        int col = y * 128 + 16 * t + c0;
        float bv1 = b1[col];
#pragma unroll
        for (int r = 0; r < 4; r++) {
            float xv = acc[t][r] + bv1;
            xv = xv / (1.f + __expf(-xv));
            u[(size_t)(m0 + R4 + r) * FF + col] = f2b(xv);
        }
    }
}

// ---------------- FFN GEMM2 (2 waves split-K) + b2 + residual + LN3 + coord ----------------
template <bool LAST>
__global__ __launch_bounds__(128)
void ffn2_ln_coord(const short* __restrict__ u, const short* __restrict__ pW2,
                   const float* __restrict__ b2, float* __restrict__ h,
                   const float* __restrict__ g, const float* __restrict__ bb,
                   const float* __restrict__ Wc, const float* __restrict__ bc,
                   const float* __restrict__ px_part, float* __restrict__ x,
                   float* __restrict__ out) {
    __shared__ float part[16][128];
    int w = threadIdx.x >> 6, l = threadIdx.x & 63;
    int m0 = blockIdx.x * 16;
    int R4 = 4 * (l >> 4), c0 = l & 15;

    f32x4 acc[8];
#pragma unroll
    for (int t = 0; t < 8; t++) acc[t] = {0.f, 0.f, 0.f, 0.f};
#pragma unroll
    for (int kt = 0; kt < 8; kt++) {
        int ktg = w * 8 + kt;
        bf16x8 av = *reinterpret_cast<const bf16x8*>(
            u + (size_t)(m0 + (l & 15)) * FF + ktg * 32 + 8 * (l >> 4));
#pragma unroll
        for (int t = 0; t < 8; t++) {
            bf16x8 bv = *reinterpret_cast<const bf16x8*>(pW2 + (t * 16 + ktg) * 512 + l * 8);
            acc[t] = __builtin_amdgcn_mfma_f32_16x16x32_bf16(av, bv, acc[t], 0, 0, 0);
        }
    }
    if (w == 1) {
#pragma unroll
        for (int t = 0; t < 8; t++)
#pragma unroll
            for (int r = 0; r < 4; r++) part[R4 + r][16 * t + c0] = acc[t][r];
    }
    __syncthreads();
    if (w == 0) {
#pragma unroll
        for (int t = 0; t < 8; t++) {
            int cc = 16 * t + c0;
            float bv2 = b2[cc];
#pragma unroll
            for (int r = 0; r < 4; r++)
                acc[t][r] += part[R4 + r][cc] + bv2 + h[(m0 + R4 + r) * DM + cc];
        }
        // LN per row (lanes 0-15 of each group hold cols of rows R4..R4+3)
        float s[4];
#pragma unroll
        for (int r = 0; r < 4; r++) {
            s[r] = 0.f;
#pragma unroll
            for (int t = 0; t < 8; t++) s[r] += acc[t][r];
        }
#pragma unroll
        for (int mm = 1; mm < 16; mm <<= 1)
#pragma unroll
            for (int r = 0; r < 4; r++) s[r] += __shfl_xor(s[r], mm);
        float mean[4], vs[4];
#pragma unroll
        for (int r = 0; r < 4; r++) mean[r] = s[r] * (1.f / DM);
#pragma unroll
        for (int r = 0; r < 4; r++) {
            vs[r] = 0.f;
#pragma unroll
            for (int t = 0; t < 8; t++) {
                float d = acc[t][r] - mean[r];
                vs[r] += d * d;
            }
        }
#pragma unroll
        for (int mm = 1; mm < 16; mm <<= 1)
#pragma unroll
            for (int r = 0; r < 4; r++) vs[r] += __shfl_xor(vs[r], mm);
        float hval[8][4];
        float dotc[4] = {0.f, 0.f, 0.f, 0.f};
#pragma unroll
        for (int r = 0; r < 4; r++) {
            float inv = rsqrtf(vs[r] * (1.f / DM) + 1e-5f);
#pragma unroll
            for (int t = 0; t < 8; t++) {
                int cc = 16 * t + c0;
                float hv = (acc[t][r] - mean[r]) * inv * g[cc] + bb[cc];
                hval[t][r] = hv;
                dotc[r] += hv * Wc[cc];
            }
        }
#pragma unroll
        for (int t = 0; t < 8; t++) {
            int cc = 16 * t + c0;
#pragma unroll
            for (int r = 0; r < 4; r++) {
                int row = m0 + R4 + r;
                h[row * DM + cc] = hval[t][r];
                if (LAST) out[row * DM + cc] = hval[t][r];
            }
        }
        // coordinate update
#pragma unroll
        for (int mm = 1; mm < 16; mm <<= 1)
#pragma unroll
            for (int r = 0; r < 4; r++) dotc[r] += __shfl_xor(dotc[r], mm);
        if (c0 < 3) {
#pragma unroll
            for (int r = 0; r < 4; r++) {
                int row = m0 + R4 + r;
                float gate = tanhf(dotc[r] + bc[0]);
                float px = 0.f;
#pragma unroll
                for (int hh = 0; hh < NH; hh++) px += px_part[(hh * NE + row) * 3 + c0];
                px *= 0.125f;
                float xv = x[row * 3 + c0];
                float nx = xv + gate * (xv - px);
                x[row * 3 + c0] = nx;
                if (LAST) out[NE * DM + row * 3 + c0] = nx;
            }
        }
    }
}

extern "C" void kernel_launch(void* const* d_in, const int* in_sizes, int n_in,
                              void* d_out, int out_size, void* d_ws, size_t ws_size,
                              hipStream_t stream) {
    const float* ef   = (const float*)d_in[0];
    const float* ec   = (const float*)d_in[1];
    const int*   eidx = (const int*)d_in[2];
    const float* nc   = (const float*)d_in[3];
    const int*   bids = (const int*)d_in[4];
    const float* Wo_a = (const float*)d_in[8];
    const float* Wo_e = (const float*)d_in[12];
    const float* b1   = (const float*)d_in[14];
    const float* b2   = (const float*)d_in[16];
    const float* ln1g = (const float*)d_in[17];
    const float* ln1b = (const float*)d_in[18];
    const float* ln2g = (const float*)d_in[19];
    const float* ln2b = (const float*)d_in[20];
    const float* ln3g = (const float*)d_in[21];
    const float* ln3b = (const float*)d_in[22];
    const float* Wc   = (const float*)d_in[24];
    const float* bc   = (const float*)d_in[25];
    float* out = (float*)d_out;

    char* w = (char*)d_ws;
    auto carve = [&](size_t bytes) { char* p = w; w += ((bytes + 255) / 256) * 256; return p; };
    int4*  meta  = (int4*)carve((size_t)NE * 16);
    float* x     = (float*)carve((size_t)NE * 3 * 4);
    float* pxp   = (float*)carve((size_t)NH * NE * 3 * 4);
    int*   cnt_a = (int*)carve((size_t)NE * 4);
    int*   cnt_e = (int*)carve((size_t)NE * 4);
    u16*   idx_a = (u16*)carve((size_t)NE * CAP * 2);
    u16*   idx_e = (u16*)carve((size_t)NE * CAP * 2);
    float* rbf   = (float*)carve((size_t)NE * NR * 4);
    float* h     = (float*)carve((size_t)NE * DM * 4);
    float* hn    = (float*)carve((size_t)NE * DM * 4);
    float* q     = (float*)carve((size_t)NE * DM * 4);
    float* k     = (float*)carve((size_t)NE * DM * 4);
    float* v     = (float*)carve((size_t)NE * DM * 4);
    short* u     = (short*)carve((size_t)NE * FF * 2);
    short* pk    = (short*)carve((size_t)NL * PK_LAYER * 2);

    WSrc ws;
    ws.W[0] = (const float*)d_in[5];   ws.W[1] = (const float*)d_in[6];
    ws.W[2] = (const float*)d_in[7];   ws.W[3] = (const float*)d_in[8];
    ws.W[4] = (const float*)d_in[9];   ws.W[5] = (const float*)d_in[10];
    ws.W[6] = (const float*)d_in[11];  ws.W[7] = (const float*)d_in[12];
    ws.W[8] = (const float*)d_in[13];  ws.W[9] = (const float*)d_in[15];
    ws.W[10] = (const float*)d_in[23];
    pack_w<<<(NL * PK_LAYER + 255) / 256, 256, 0, stream>>>(ws, pk);

    prep_kernel<<<NE, 64, 0, stream>>>(ef, ec, eidx, nc, bids, h, x, rbf, meta);
    build_lists<<<NE, 64, 0, stream>>>(meta, idx_a, cnt_a, idx_e, cnt_e);

    for (int l = 0; l < NL; l++) {
        const short* Lb = pk + (size_t)l * PK_LAYER;

        // hn = h + rbf@Wrbf; q,k,v = hn @ {Wq,Wk,Wv}_a
        qkv_mfma<true><<<dim3(192, 3), 64, 0, stream>>>(h, rbf, Lb + PK_QKV_A,
                                                        Lb + PK_WRBF, hn, q, k, v);
        attn_wo_ln<true><<<NE, 512, 0, stream>>>(q, k, v, x, idx_a, cnt_a,
                                                 Wo_a + (size_t)l * DM * DM, hn, h,
                                                 ln1g + l * DM, ln1b + l * DM, pxp);
        qkv_mfma<false><<<dim3(192, 3), 64, 0, stream>>>(h, nullptr, Lb + PK_QKV_E,
                                                         nullptr, nullptr, q, k, v);
        attn_wo_ln<false><<<NE, 512, 0, stream>>>(q, k, v, x, idx_e, cnt_e,
                                                  Wo_e + (size_t)l * DM * DM, h, h,
                                                  ln2g + l * DM, ln2b + l * DM, nullptr);
        ffn1_mfma<<<dim3(192, 4), 64, 0, stream>>>(h, Lb + PK_W1, b1 + l * FF, u);
        if (l < NL - 1)
            ffn2_ln_coord<false><<<192, 128, 0, stream>>>(u, Lb + PK_W2, b2 + l * DM, h,
                                                          ln3g + l * DM, ln3b + l * DM,
                                                          Wc + l * DM, bc + l, pxp, x, out);
        else
            ffn2_ln_coord<true><<<192, 128, 0, stream>>>(u, Lb + PK_W2, b2 + l * DM, h,
                                                         ln3g + l * DM, ln3b + l * DM,
                                                         Wc + l * DM, bc + l, pxp, x, out);
    }
}

// Round 7
// 244.271 us; speedup vs baseline: 1.7613x; 1.7613x over previous
//
#include <hip/hip_runtime.h>
#include <hip/hip_bf16.h>

typedef unsigned short u16;
typedef __attribute__((ext_vector_type(4))) float f32x4;
typedef __attribute__((ext_vector_type(8))) short bf16x8;

#define NE 3072
#define DM 128
#define NH 8
#define HD 16
#define NL 3
#define NR 64
#define FF 512
#define CUT 10.0f
#define CAP 96

// packed bf16 weight layout offsets (per layer, in elements)
#define PK_QKV_A 0
#define PK_WO_A  49152
#define PK_QKV_E 65536
#define PK_WO_E  114688
#define PK_W1    131072
#define PK_W2    196608
#define PK_WRBF  262144
#define PK_LAYER 270336

__device__ __forceinline__ short f2b(float f) {
    unsigned u = __float_as_uint(f);
    unsigned r = (u + 0x7FFFu + ((u >> 16) & 1u)) >> 16;
    return (short)r;
}

// A fragment from row-major f32: lane l -> row (l&15), k = kbase+8*(l>>4)+i
__device__ __forceinline__ bf16x8 load_a(const float* A, int rowoff, int kbase) {
    const float4* p = reinterpret_cast<const float4*>(A + rowoff + kbase);
    float4 f0 = p[0], f1 = p[1];
    bf16x8 r;
    r[0] = f2b(f0.x); r[1] = f2b(f0.y); r[2] = f2b(f0.z); r[3] = f2b(f0.w);
    r[4] = f2b(f1.x); r[5] = f2b(f1.y); r[6] = f2b(f1.z); r[7] = f2b(f1.w);
    return r;
}

// ---------------- pack all weights into bf16 fragment-linear layout ----------------
struct WSrc { const float* W[11]; };

__global__ __launch_bounds__(256)
void pack_w(WSrc ws, short* __restrict__ dst) {
    int gid = blockIdx.x * 256 + threadIdx.x;
    if (gid >= NL * PK_LAYER) return;
    int layer = gid / PK_LAYER, e = gid % PK_LAYER;
    int kind, off, K, N;
    if (e < 49152)       { kind = e / 16384;            off = e % 16384;      K = 128; N = 128; }
    else if (e < 65536)  { kind = 3;                    off = e - 49152;      K = 128; N = 128; }
    else if (e < 114688) { kind = 4 + (e - 65536) / 16384; off = (e - 65536) % 16384; K = 128; N = 128; }
    else if (e < 131072) { kind = 7;                    off = e - 114688;     K = 128; N = 128; }
    else if (e < 196608) { kind = 8;                    off = e - 131072;     K = 128; N = 512; }
    else if (e < 262144) { kind = 9;                    off = e - 196608;     K = 512; N = 128; }
    else                 { kind = 10;                   off = e - 262144;     K = 64;  N = 128; }
    int i = off & 7, lane = (off >> 3) & 63, ft = off >> 9;
    int KT = K >> 5;
    int kt = ft % KT, nt = ft / KT;
    int n = nt * 16 + (lane & 15);
    int k = kt * 32 + 8 * (lane >> 4) + i;
    const float* W = ws.W[kind] + (size_t)layer * K * N;
    dst[gid] = f2b(W[k * N + n]);
}

// ---------------- prep: meta, h=ef, x=ec, rbf ----------------
__global__ __launch_bounds__(64)
void prep_kernel(const float* __restrict__ ef, const float* __restrict__ ec,
                 const int* __restrict__ eidx, const float* __restrict__ nc,
                 const int* __restrict__ bids,
                 float* __restrict__ h, float* __restrict__ x,
                 float* __restrict__ rbf, int4* __restrict__ meta) {
    int e = blockIdx.x, lane = threadIdx.x;
    int s = eidx[e], d = eidx[NE + e];
    if (lane == 0) meta[e] = make_int4(s, d, bids[s], bids[d]);
    h[e * DM + lane]      = ef[e * DM + lane];
    h[e * DM + 64 + lane] = ef[e * DM + 64 + lane];
    if (lane < 3) x[e * 3 + lane] = ec[e * 3 + lane];
    float dx = nc[d * 3 + 0] - nc[s * 3 + 0];
    float dy = nc[d * 3 + 1] - nc[s * 3 + 1];
    float dz = nc[d * 3 + 2] - nc[s * 3 + 2];
    float dist = sqrtf(dx * dx + dy * dy + dz * dz);
    float t = fminf(fmaxf(dist / CUT, 0.f), 1.f);
    float fc = 0.5f * (cosf(3.14159265358979f * t) + 1.f);
    float width = CUT / NR;
    float center = (CUT * lane) / (NR - 1);
    float u = (dist - center) / width;
    rbf[e * NR + lane] = expf(-u * u) * fc;
}

// ---------------- build neighbor lists ----------------
__global__ __launch_bounds__(64)
void build_lists(const int4* __restrict__ meta,
                 u16* __restrict__ idx_a, int* __restrict__ cnt_a,
                 u16* __restrict__ idx_e, int* __restrict__ cnt_e) {
    __shared__ int ca, ce;
    __shared__ u16 ba[CAP], be[CAP];
    int i = blockIdx.x, lane = threadIdx.x;
    if (lane == 0) { ca = 0; ce = 0; }
    __syncthreads();
    int4 mi = meta[i];
    for (int j = lane; j < NE; j += 64) {
        int4 mj = meta[j];
        bool intra_b = (mi.z == mj.z) && (mi.w == mj.w);
        bool share = (mi.x == mj.x) || (mi.x == mj.y) ||
                     (mi.y == mj.x) || (mi.y == mj.y);
        bool oka = intra_b || (i == j);
        bool oke = (share && !intra_b) || (i == j);
        if (oka) { int p = atomicAdd(&ca, 1); if (p < CAP) ba[p] = (u16)j; }
        if (oke) { int p = atomicAdd(&ce, 1); if (p < CAP) be[p] = (u16)j; }
    }
    __syncthreads();
    int na = min(ca, CAP), ne_ = min(ce, CAP);
    if (lane == 0) { cnt_a[i] = na; cnt_e[i] = ne_; }
    for (int p = lane; p < na; p += 64) idx_a[i * CAP + p] = ba[p];
    for (int p = lane; p < ne_; p += 64) idx_e[i * CAP + p] = be[p];
}

// ---------------- QKV projection, 1 wave per block: 16 rows x 128 cols ----------------
// RBF=true: hn = h + rbf@Wrbf (written by y==0), and QKV computed from hn
template <bool RBF>
__global__ __launch_bounds__(64)
void qkv_mfma(const float* __restrict__ h, const float* __restrict__ rbf,
              const short* __restrict__ pQKV, const short* __restrict__ pWr,
              float* __restrict__ hn,
              float* __restrict__ q, float* __restrict__ k2, float* __restrict__ v) {
    __shared__ float hs[16][136];
    int l = threadIdx.x;
    int m0 = blockIdx.x * 16, y = blockIdx.y;
    int arow = m0 + (l & 15);
    int R4 = 4 * (l >> 4), c0 = l & 15;
    const short* Bsec = pQKV + y * 16384;

    if (RBF) {
        f32x4 acc[8];
#pragma unroll
        for (int t = 0; t < 8; t++) acc[t] = {0.f, 0.f, 0.f, 0.f};
#pragma unroll
        for (int kt = 0; kt < 2; kt++) {
            bf16x8 av = load_a(rbf, arow * NR, kt * 32 + 8 * (l >> 4));
#pragma unroll
            for (int t = 0; t < 8; t++) {
                bf16x8 bv = *reinterpret_cast<const bf16x8*>(pWr + (t * 2 + kt) * 512 + l * 8);
                acc[t] = __builtin_amdgcn_mfma_f32_16x16x32_bf16(av, bv, acc[t], 0, 0, 0);
            }
        }
#pragma unroll
        for (int t = 0; t < 8; t++)
#pragma unroll
            for (int r = 0; r < 4; r++) {
                float z = acc[t][r] + h[(m0 + R4 + r) * DM + 16 * t + c0];
                hs[R4 + r][16 * t + c0] = z;
                if (y == 0) hn[(m0 + R4 + r) * DM + 16 * t + c0] = z;
            }
        __syncthreads();
    }

    f32x4 o[8];
#pragma unroll
    for (int t = 0; t < 8; t++) o[t] = {0.f, 0.f, 0.f, 0.f};
#pragma unroll
    for (int kt = 0; kt < 4; kt++) {
        bf16x8 av;
        if (RBF) {
            const float4* pp = reinterpret_cast<const float4*>(&hs[l & 15][kt * 32 + 8 * (l >> 4)]);
            float4 f0 = pp[0], f1 = pp[1];
            av[0] = f2b(f0.x); av[1] = f2b(f0.y); av[2] = f2b(f0.z); av[3] = f2b(f0.w);
            av[4] = f2b(f1.x); av[5] = f2b(f1.y); av[6] = f2b(f1.z); av[7] = f2b(f1.w);
        } else {
            av = load_a(h, arow * DM, kt * 32 + 8 * (l >> 4));
        }
#pragma unroll
        for (int t = 0; t < 8; t++) {
            bf16x8 bv = *reinterpret_cast<const bf16x8*>(Bsec + (t * 4 + kt) * 512 + l * 8);
            o[t] = __builtin_amdgcn_mfma_f32_16x16x32_bf16(av, bv, o[t], 0, 0, 0);
        }
    }
    float* outs = (y == 0) ? q : (y == 1) ? k2 : v;
#pragma unroll
    for (int t = 0; t < 8; t++)
#pragma unroll
        for (int r = 0; r < 4; r++)
            outs[(m0 + R4 + r) * DM + 16 * t + c0] = o[t][r];
}

// ---------------- fused attention (16 rows/block) + MFMA Wo + residual + LN ----------------
// 8 waves: wave w = head w for all 16 rows; 4 lanes per (row,head)
template <bool INTRA>
__global__ __launch_bounds__(512)
void attn16_wo_ln(const float* __restrict__ q, const float* __restrict__ k,
                  const float* __restrict__ v, const float* __restrict__ xw,
                  const u16* __restrict__ idx, const int* __restrict__ cnt,
                  const short* __restrict__ pWo, const float* __restrict__ hres,
                  float* __restrict__ hout, const float* __restrict__ g,
                  const float* __restrict__ b, float* __restrict__ px_part) {
    __shared__ short o_sb[16][136];   // bf16 o tile (padded: stride 272B)
    __shared__ float zs[16][136];     // z = o@Wo + hres tile (padded)
    int m0 = blockIdx.x * 16;
    int w = threadIdx.x >> 6, l = threadIdx.x & 63;
    int rowl = l >> 2, sub = l & 3;
    int row = m0 + rowl;

    // ---- attention ----
    float qreg[HD];
    const float* qp = q + row * DM + w * HD;
#pragma unroll
    for (int d = 0; d < HD; d++) qreg[d] = qp[d];

    int n = cnt[row];
    float m = -1e30f, li = 0.f;
    float acc[HD + 3];
#pragma unroll
    for (int d = 0; d < HD + 3; d++) acc[d] = 0.f;

    for (int p = sub; p < n; p += 4) {
        int j = idx[row * CAP + p];
        const float* kp = k + j * DM + w * HD;
        float s = 0.f;
#pragma unroll
        for (int d = 0; d < HD; d++) s += qreg[d] * kp[d];
        s *= 0.25f;
        if (s > m) {
            float corr = __expf(m - s);
            m = s; li *= corr;
#pragma unroll
            for (int d = 0; d < HD + 3; d++) acc[d] *= corr;
        }
        float pw = __expf(s - m);
        li += pw;
        const float* vp = v + j * DM + w * HD;
#pragma unroll
        for (int d = 0; d < HD; d++) acc[d] += pw * vp[d];
        if (INTRA) {
            const float* xp = xw + j * 3;
#pragma unroll
            for (int c = 0; c < 3; c++) acc[HD + c] += pw * xp[c];
        }
    }
    // merge the 4 sub-lanes of each row group
    float mAll = m;
    mAll = fmaxf(mAll, __shfl_xor(mAll, 1));
    mAll = fmaxf(mAll, __shfl_xor(mAll, 2));
    float cf = __expf(m - mAll);
    li *= cf;
#pragma unroll
    for (int d = 0; d < HD + 3; d++) acc[d] *= cf;
#pragma unroll
    for (int off = 1; off <= 2; off <<= 1) {
        li += __shfl_xor(li, off);
#pragma unroll
        for (int d = 0; d < HD + 3; d++) acc[d] += __shfl_xor(acc[d], off);
    }
    if (sub == 0) {
        float inv = 1.f / li;
#pragma unroll
        for (int d = 0; d < HD; d++) o_sb[rowl][w * HD + d] = f2b(acc[d] * inv);
        if (INTRA) {
            float* pp = px_part + (w * NE + row) * 3;
            pp[0] = acc[HD + 0] * inv;
            pp[1] = acc[HD + 1] * inv;
            pp[2] = acc[HD + 2] * inv;
        }
    }
    __syncthreads();

    // ---- Wo MFMA: wave w computes its 16-col tile ----
    int arow = l & 15, g4 = l >> 4;
    f32x4 dacc = {0.f, 0.f, 0.f, 0.f};
#pragma unroll
    for (int kt = 0; kt < 4; kt++) {
        bf16x8 av = *reinterpret_cast<const bf16x8*>(&o_sb[arow][kt * 32 + 8 * g4]);
        bf16x8 bv = *reinterpret_cast<const bf16x8*>(pWo + (w * 4 + kt) * 512 + l * 8);
        dacc = __builtin_amdgcn_mfma_f32_16x16x32_bf16(av, bv, dacc, 0, 0, 0);
    }
    int R4 = 4 * g4, c0 = l & 15;
#pragma unroll
    for (int r = 0; r < 4; r++)
        zs[R4 + r][w * 16 + c0] = dacc[r] + hres[(m0 + R4 + r) * DM + w * 16 + c0];
    __syncthreads();

    // ---- LN: wave w handles rows 2w, 2w+1 ----
#pragma unroll
    for (int rr = 0; rr < 2; rr++) {
        int r = 2 * w + rr;
        float z0 = zs[r][l], z1 = zs[r][l + 64];
        float s = z0 + z1;
#pragma unroll
        for (int off = 32; off; off >>= 1) s += __shfl_xor(s, off);
        float mean = s * (1.f / DM);
        float d0 = z0 - mean, d1 = z1 - mean;
        float vs = d0 * d0 + d1 * d1;
#pragma unroll
        for (int off = 32; off; off >>= 1) vs += __shfl_xor(vs, off);
        float inv = rsqrtf(vs * (1.f / DM) + 1e-5f);
        hout[(m0 + r) * DM + l]      = d0 * inv * g[l] + b[l];
        hout[(m0 + r) * DM + 64 + l] = d1 * inv * g[64 + l] + b[64 + l];
    }
}

// ---------------- FFN GEMM1 + silu -> u (bf16 row-major [NE][FF]) ----------------
__global__ __launch_bounds__(64)
void ffn1_mfma(const float* __restrict__ h, const short* __restrict__ pW1,
               const float* __restrict__ b1, short* __restrict__ u) {
    int l = threadIdx.x;
    int m0 = blockIdx.x * 16, y = blockIdx.y;
    int arow = m0 + (l & 15);
    f32x4 acc[8];
#pragma unroll
    for (int t = 0; t < 8; t++) acc[t] = {0.f, 0.f, 0.f, 0.f};
#pragma unroll
    for (int kt = 0; kt < 4; kt++) {
        bf16x8 av = load_a(h, arow * DM, kt * 32 + 8 * (l >> 4));
#pragma unroll
        for (int t = 0; t < 8; t++) {
            bf16x8 bv = *reinterpret_cast<const bf16x8*>(pW1 + ((y * 8 + t) * 4 + kt) * 512 + l * 8);
            acc[t] = __builtin_amdgcn_mfma_f32_16x16x32_bf16(av, bv, acc[t], 0, 0, 0);
        }
    }
    int R4 = 4 * (l >> 4), c0 = l & 15;
#pragma unroll
    for (int t = 0; t < 8; t++) {
        int col = y * 128 + 16 * t + c0;
        float bv1 = b1[col];
#pragma unroll
        for (int r = 0; r < 4; r++) {
            float xv = acc[t][r] + bv1;
            xv = xv / (1.f + __expf(-xv));
            u[(size_t)(m0 + R4 + r) * FF + col] = f2b(xv);
        }
    }
}

// ---------------- FFN GEMM2 (2 waves split-K) + b2 + residual + LN3 + coord ----------------
template <bool LAST>
__global__ __launch_bounds__(128)
void ffn2_ln_coord(const short* __restrict__ u, const short* __restrict__ pW2,
                   const float* __restrict__ b2, float* __restrict__ h,
                   const float* __restrict__ g, const float* __restrict__ bb,
                   const float* __restrict__ Wc, const float* __restrict__ bc,
                   const float* __restrict__ px_part, float* __restrict__ x,
                   float* __restrict__ out) {
    __shared__ float part[16][128];
    int w = threadIdx.x >> 6, l = threadIdx.x & 63;
    int m0 = blockIdx.x * 16;
    int R4 = 4 * (l >> 4), c0 = l & 15;

    f32x4 acc[8];
#pragma unroll
    for (int t = 0; t < 8; t++) acc[t] = {0.f, 0.f, 0.f, 0.f};
#pragma unroll
    for (int kt = 0; kt < 8; kt++) {
        int ktg = w * 8 + kt;
        bf16x8 av = *reinterpret_cast<const bf16x8*>(
            u + (size_t)(m0 + (l & 15)) * FF + ktg * 32 + 8 * (l >> 4));
#pragma unroll
        for (int t = 0; t < 8; t++) {
            bf16x8 bv = *reinterpret_cast<const bf16x8*>(pW2 + (t * 16 + ktg) * 512 + l * 8);
            acc[t] = __builtin_amdgcn_mfma_f32_16x16x32_bf16(av, bv, acc[t], 0, 0, 0);
        }
    }
    if (w == 1) {
#pragma unroll
        for (int t = 0; t < 8; t++)
#pragma unroll
            for (int r = 0; r < 4; r++) part[R4 + r][16 * t + c0] = acc[t][r];
    }
    __syncthreads();
    if (w == 0) {
#pragma unroll
        for (int t = 0; t < 8; t++) {
            int cc = 16 * t + c0;
            float bv2 = b2[cc];
#pragma unroll
            for (int r = 0; r < 4; r++)
                acc[t][r] += part[R4 + r][cc] + bv2 + h[(m0 + R4 + r) * DM + cc];
        }
        float s[4];
#pragma unroll
        for (int r = 0; r < 4; r++) {
            s[r] = 0.f;
#pragma unroll
            for (int t = 0; t < 8; t++) s[r] += acc[t][r];
        }
#pragma unroll
        for (int mm = 1; mm < 16; mm <<= 1)
#pragma unroll
            for (int r = 0; r < 4; r++) s[r] += __shfl_xor(s[r], mm);
        float mean[4], vs[4];
#pragma unroll
        for (int r = 0; r < 4; r++) mean[r] = s[r] * (1.f / DM);
#pragma unroll
        for (int r = 0; r < 4; r++) {
            vs[r] = 0.f;
#pragma unroll
            for (int t = 0; t < 8; t++) {
                float d = acc[t][r] - mean[r];
                vs[r] += d * d;
            }
        }
#pragma unroll
        for (int mm = 1; mm < 16; mm <<= 1)
#pragma unroll
            for (int r = 0; r < 4; r++) vs[r] += __shfl_xor(vs[r], mm);
        float hval[8][4];
        float dotc[4] = {0.f, 0.f, 0.f, 0.f};
#pragma unroll
        for (int r = 0; r < 4; r++) {
            float inv = rsqrtf(vs[r] * (1.f / DM) + 1e-5f);
#pragma unroll
            for (int t = 0; t < 8; t++) {
                int cc = 16 * t + c0;
                float hv = (acc[t][r] - mean[r]) * inv * g[cc] + bb[cc];
                hval[t][r] = hv;
                dotc[r] += hv * Wc[cc];
            }
        }
#pragma unroll
        for (int t = 0; t < 8; t++) {
            int cc = 16 * t + c0;
#pragma unroll
            for (int r = 0; r < 4; r++) {
                int row = m0 + R4 + r;
                h[row * DM + cc] = hval[t][r];
                if (LAST) out[row * DM + cc] = hval[t][r];
            }
        }
#pragma unroll
        for (int mm = 1; mm < 16; mm <<= 1)
#pragma unroll
            for (int r = 0; r < 4; r++) dotc[r] += __shfl_xor(dotc[r], mm);
        if (c0 < 3) {
#pragma unroll
            for (int r = 0; r < 4; r++) {
                int row = m0 + R4 + r;
                float gate = tanhf(dotc[r] + bc[0]);
                float px = 0.f;
#pragma unroll
                for (int hh = 0; hh < NH; hh++) px += px_part[(hh * NE + row) * 3 + c0];
                px *= 0.125f;
                float xv = x[row * 3 + c0];
                float nx = xv + gate * (xv - px);
                x[row * 3 + c0] = nx;
                if (LAST) out[NE * DM + row * 3 + c0] = nx;
            }
        }
    }
}

extern "C" void kernel_launch(void* const* d_in, const int* in_sizes, int n_in,
                              void* d_out, int out_size, void* d_ws, size_t ws_size,
                              hipStream_t stream) {
    const float* ef   = (const float*)d_in[0];
    const float* ec   = (const float*)d_in[1];
    const int*   eidx = (const int*)d_in[2];
    const float* nc   = (const float*)d_in[3];
    const int*   bids = (const int*)d_in[4];
    const float* b1   = (const float*)d_in[14];
    const float* b2   = (const float*)d_in[16];
    const float* ln1g = (const float*)d_in[17];
    const float* ln1b = (const float*)d_in[18];
    const float* ln2g = (const float*)d_in[19];
    const float* ln2b = (const float*)d_in[20];
    const float* ln3g = (const float*)d_in[21];
    const float* ln3b = (const float*)d_in[22];
    const float* Wc   = (const float*)d_in[24];
    const float* bc   = (const float*)d_in[25];
    float* out = (float*)d_out;

    char* w = (char*)d_ws;
    auto carve = [&](size_t bytes) { char* p = w; w += ((bytes + 255) / 256) * 256; return p; };
    int4*  meta  = (int4*)carve((size_t)NE * 16);
    float* x     = (float*)carve((size_t)NE * 3 * 4);
    float* pxp   = (float*)carve((size_t)NH * NE * 3 * 4);
    int*   cnt_a = (int*)carve((size_t)NE * 4);
    int*   cnt_e = (int*)carve((size_t)NE * 4);
    u16*   idx_a = (u16*)carve((size_t)NE * CAP * 2);
    u16*   idx_e = (u16*)carve((size_t)NE * CAP * 2);
    float* rbf   = (float*)carve((size_t)NE * NR * 4);
    float* h     = (float*)carve((size_t)NE * DM * 4);
    float* hn    = (float*)carve((size_t)NE * DM * 4);
    float* q     = (float*)carve((size_t)NE * DM * 4);
    float* k     = (float*)carve((size_t)NE * DM * 4);
    float* v     = (float*)carve((size_t)NE * DM * 4);
    short* u     = (short*)carve((size_t)NE * FF * 2);
    short* pk    = (short*)carve((size_t)NL * PK_LAYER * 2);

    WSrc ws;
    ws.W[0] = (const float*)d_in[5];   ws.W[1] = (const float*)d_in[6];
    ws.W[2] = (const float*)d_in[7];   ws.W[3] = (const float*)d_in[8];
    ws.W[4] = (const float*)d_in[9];   ws.W[5] = (const float*)d_in[10];
    ws.W[6] = (const float*)d_in[11];  ws.W[7] = (const float*)d_in[12];
    ws.W[8] = (const float*)d_in[13];  ws.W[9] = (const float*)d_in[15];
    ws.W[10] = (const float*)d_in[23];
    pack_w<<<(NL * PK_LAYER + 255) / 256, 256, 0, stream>>>(ws, pk);

    prep_kernel<<<NE, 64, 0, stream>>>(ef, ec, eidx, nc, bids, h, x, rbf, meta);
    build_lists<<<NE, 64, 0, stream>>>(meta, idx_a, cnt_a, idx_e, cnt_e);

    for (int l = 0; l < NL; l++) {
        const short* Lb = pk + (size_t)l * PK_LAYER;

        qkv_mfma<true><<<dim3(192, 3), 64, 0, stream>>>(h, rbf, Lb + PK_QKV_A,
                                                        Lb + PK_WRBF, hn, q, k, v);
        attn16_wo_ln<true><<<192, 512, 0, stream>>>(q, k, v, x, idx_a, cnt_a,
                                                    Lb + PK_WO_A, hn, h,
                                                    ln1g + l * DM, ln1b + l * DM, pxp);
        qkv_mfma<false><<<dim3(192, 3), 64, 0, stream>>>(h, nullptr, Lb + PK_QKV_E,
                                                         nullptr, nullptr, q, k, v);
        attn16_wo_ln<false><<<192, 512, 0, stream>>>(q, k, v, x, idx_e, cnt_e,
                                                     Lb + PK_WO_E, h, h,
                                                     ln2g + l * DM, ln2b + l * DM, nullptr);
        ffn1_mfma<<<dim3(192, 4), 64, 0, stream>>>(h, Lb + PK_W1, b1 + l * FF, u);
        if (l < NL - 1)
            ffn2_ln_coord<false><<<192, 128, 0, stream>>>(u, Lb + PK_W2, b2 + l * DM, h,
                                                          ln3g + l * DM, ln3b + l * DM,
                                                          Wc + l * DM, bc + l, pxp, x, out);
        else
            ffn2_ln_coord<true><<<192, 128, 0, stream>>>(u, Lb + PK_W2, b2 + l * DM, h,
                                                         ln3g + l * DM, ln3b + l * DM,
                                                         Wc + l * DM, bc + l, pxp, x, out);
    }
}